// Round 2
// baseline (142.973 us; speedup 1.0000x reference)
//
#include <hip/hip_runtime.h>

// Flash attention forward, fp32 in/out, fp16 MFMA compute.
// B=8, SQ=SK=4096, D=64. scores = (Q/x5) K^T ; softmax ; O = P V.
// R14 = R13 bugfix. R13's 32x32x16 restructure (swapped QK^T, in-register
// softmax, permlane P redistribution) failed accuracy: the raw-asm
// v_permlane32_swap with BOTH operands = the same value (rm self-swap, ll
// self-swap) risks single-register coalescing -> degenerate half-swap ->
// the two hi-halves of a softmax row use DIFFERENT maxima (O(1) error).
// Fix: cross-half combines via __shfl_xor(x,32) (R12-proven primitive);
// PA_SLICE via __builtin_amdgcn_permlane32_swap (m214-verified recipe,
// distinct operands, compiler-allocated dual results).
// Structure: S^T = K Q^T puts q = lane&31; keys in regs; row-max = in-lane
// fmax tree + 1 cross-half combine; P->fp16 fragments via cvt_pkrtz +
// permlane32_swap (no sP LDS round trip). PV computes O^T = V^T P^T.
// BQ=128 (32 q/wave), grid 1024 = 4 blocks/CU, LDS 32KB.

typedef _Float16 f16x8 __attribute__((ext_vector_type(8)));
typedef _Float16 f16x4 __attribute__((ext_vector_type(4)));
typedef __fp16   h16x2 __attribute__((ext_vector_type(2)));
typedef float    f32x4 __attribute__((ext_vector_type(4)));
typedef float    f32x16 __attribute__((ext_vector_type(16)));

constexpr int kB  = 8;
constexpr int kSQ = 4096;
constexpr int kSK = 4096;
constexpr int kD  = 64;
constexpr int KSPLIT = 4;
constexpr int SKH = kSK / KSPLIT;     // 1024 keys per split
constexpr int BQ  = 128;              // 4 waves x 32 Q rows
constexpr int BK  = 64;
constexpr size_t APART = (size_t)kB * kSQ * kD;
constexpr float kLog2e = 1.44269504088896340736f;

static __device__ __forceinline__ f16x4 pack4(float a, float b, float c, float d) {
    h16x2 p0 = __builtin_amdgcn_cvt_pkrtz(a, b);
    h16x2 p1 = __builtin_amdgcn_cvt_pkrtz(c, d);
    f16x4 r;
    r[0] = (_Float16)p0[0]; r[1] = (_Float16)p0[1];
    r[2] = (_Float16)p1[0]; r[3] = (_Float16)p1[1];
    return r;
}
static __device__ __forceinline__ f16x8 pack8(const float4& a, const float4& c) {
    f16x4 lo = pack4(a.x, a.y, a.z, a.w);
    f16x4 hi = pack4(c.x, c.y, c.z, c.w);
    f16x8 f;
    f[0] = lo[0]; f[1] = lo[1]; f[2] = lo[2]; f[3] = lo[3];
    f[4] = hi[0]; f[5] = hi[1]; f[6] = hi[2]; f[7] = hi[3];
    return f;
}
static __device__ __forceinline__ unsigned pkrtz_u(float a, float b) {
    union { h16x2 h; unsigned u; } cv;
    cv.h = __builtin_amdgcn_cvt_pkrtz(a, b);
    return cv.u;
}

typedef const __attribute__((address_space(1))) unsigned int* gu32p;
typedef __attribute__((address_space(3))) unsigned int* lu32p;
static __device__ __forceinline__ void gload_lds16(const void* g, void* l) {
    __builtin_amdgcn_global_load_lds((gu32p)g, (lu32p)l, 16, 0, 0);
}

// P slice (8 regs of one 32-key C-block) -> f16x8 PV fragment.
// C/D rows: key = (r&3)+8*(r>>2)+4*hi. Pair cvtpk(p[2i],p[2i+1]) with
// cvtpk(p[2i+4],p[2i+5]); one permlane32_swap fills two output words
// (guide §B m214-verified recipe). Result: pa(hi,j) = P[base + 8*hi + j][q].
#define PA_SLICE(dst, sv, rb) do {                                          \
    unsigned c0 = pkrtz_u((sv)[(rb)+0], (sv)[(rb)+1]);                      \
    unsigned c1 = pkrtz_u((sv)[(rb)+2], (sv)[(rb)+3]);                      \
    unsigned c2 = pkrtz_u((sv)[(rb)+4], (sv)[(rb)+5]);                      \
    unsigned c3 = pkrtz_u((sv)[(rb)+6], (sv)[(rb)+7]);                      \
    auto r02 = __builtin_amdgcn_permlane32_swap(c0, c2, false, false);      \
    auto r13 = __builtin_amdgcn_permlane32_swap(c1, c3, false, false);      \
    union { unsigned u[4]; f16x8 v; } _r;                                   \
    _r.u[0] = r02[0]; _r.u[1] = r13[0]; _r.u[2] = r02[1]; _r.u[3] = r13[1]; \
    dst = _r.v;                                                             \
} while (0)

// ---------------- pre-pass: K -> Kh (swizzled fp16), V -> Vt (transposed,
// tiled, swizzled fp16). Kh[b][k][blk fb^(k&7)][8]; Vt[b][kt][f][blk kb^(f&7)][8].
__global__ __launch_bounds__(256, 2)
void fattn_prepass(const float* __restrict__ Kg,
                   const float* __restrict__ Vg,
                   _Float16* __restrict__ Kh,
                   _Float16* __restrict__ Vt)
{
    __shared__ _Float16 tr[kD][BK];

    const int tid = threadIdx.x;
    const int kt  = blockIdx.x;
    const int b   = blockIdx.y;

    const int k = tid >> 2;
    const int p = tid & 3;
    const int gk = kt * BK + k;

    {
        const float* src = Kg + ((size_t)b * kSK + gk) * kD + p * 16;
        const float4 a0 = *(const float4*)(src + 0);
        const float4 a1 = *(const float4*)(src + 4);
        const float4 a2 = *(const float4*)(src + 8);
        const float4 a3 = *(const float4*)(src + 12);
        _Float16* dst = Kh + ((size_t)b * kSK + gk) * kD;
        const int fb0 = 2 * p, fb1 = 2 * p + 1;
        *(f16x8*)&dst[(fb0 ^ (gk & 7)) * 8] = pack8(a0, a1);
        *(f16x8*)&dst[(fb1 ^ (gk & 7)) * 8] = pack8(a2, a3);
    }
    {
        const float* src = Vg + ((size_t)b * kSK + gk) * kD + p * 16;
        const float4 a0 = *(const float4*)(src + 0);
        const float4 a1 = *(const float4*)(src + 4);
        const float4 a2 = *(const float4*)(src + 8);
        const float4 a3 = *(const float4*)(src + 12);
        const float v[16] = {a0.x,a0.y,a0.z,a0.w, a1.x,a1.y,a1.z,a1.w,
                             a2.x,a2.y,a2.z,a2.w, a3.x,a3.y,a3.z,a3.w};
#pragma unroll
        for (int j = 0; j < 16; ++j)
            tr[p * 16 + j][k] = (_Float16)v[j];
    }
    __syncthreads();
    {
        const int f  = tid >> 2;
        const int p2 = tid & 3;
        const f16x8 b0 = *(const f16x8*)&tr[f][p2 * 16 + 0];
        const f16x8 b1 = *(const f16x8*)&tr[f][p2 * 16 + 8];
        _Float16* dst = Vt + (((size_t)b * 64 + kt) * kD + f) * BK;
        const int kb0 = 2 * p2, kb1 = 2 * p2 + 1;
        *(f16x8*)&dst[(kb0 ^ (f & 7)) * 8] = b0;
        *(f16x8*)&dst[(kb1 ^ (f & 7)) * 8] = b1;
    }
}

// ---------------- main partial kernel (32x32x16 MFMA) ----------------
__global__ __launch_bounds__(256, 4)
void fattn_partial(const float* __restrict__ Qg,
                   const _Float16* __restrict__ Kh,
                   const _Float16* __restrict__ Vt,
                   const float* __restrict__ sdiv,
                   _Float16* __restrict__ Ap,   // [KSPLIT][B][SQ][D] unnormalized
                   float2* __restrict__ MLp)    // [KSPLIT][B][SQ] (m,l) exp2-domain
{
    __shared__ __align__(16) _Float16 sK[2][BK * kD];   // 16 KB
    __shared__ __align__(16) _Float16 sV[2][kD * BK];   // 16 KB

    const int tid  = threadIdx.x;
    const int w    = tid >> 6;
    const int lane = tid & 63;
    const int l31  = lane & 31;
    const int hi   = lane >> 5;

    // XCD-affine decode: flat = c + 32*q; c = (b,ks); all 32 q-blocks of one
    // K/V stream share an XCD (flat%8 invariant across q).
    const int flat = blockIdx.x;
    const int c    = flat & 31;
    const int qi   = flat >> 5;
    const int b    = c >> 2;      // KSPLIT = 4
    const int ks   = c & 3;
    const int qb   = qi * BQ;

    const float qscale = kLog2e / sdiv[0];   // exp2 domain

    const float* Qb = Qg + ((size_t)b * kSQ + qb) * kD;
    const _Float16* Khb = Kh + ((size_t)b * kSK + (size_t)ks * SKH) * kD;
    const _Float16* Vtb = Vt + (((size_t)b * 64 + (size_t)ks * (SKH / BK)) * kD) * BK;

    // ---- Q fragment (B operand): qf[ds][j] = Q[q][ds*16 + hi*8 + j]*qscale,
    //      q = qb + w*32 + l31 (lane-col of all MFMAs) ----
    f16x8 qf[4];
    {
        const float* qrow = Qb + (size_t)(w * 32 + l31) * kD;
#pragma unroll
        for (int ds = 0; ds < 4; ++ds) {
            const float4 a  = *(const float4*)(qrow + ds * 16 + hi * 8);
            const float4 cc = *(const float4*)(qrow + ds * 16 + hi * 8 + 4);
            float4 as = make_float4(a.x * qscale, a.y * qscale, a.z * qscale, a.w * qscale);
            float4 cs = make_float4(cc.x * qscale, cc.y * qscale, cc.z * qscale, cc.w * qscale);
            qf[ds] = pack8(as, cs);
        }
    }

    // Swizzled LDS fragment offsets (halves); identical pattern for K and V:
    // row = l31 (+32 per second block), 16B slot = (2*i + hi) ^ (row & 7).
    int offA[4];
#pragma unroll
    for (int i = 0; i < 4; ++i)
        offA[i] = l31 * 64 + (((2 * i + hi) ^ (l31 & 7)) * 8);

    // ---- async staging: 4 global_load_lds per wave (unchanged) ----
    auto stage = [&](int kt, int buf) {
        const char* gk = (const char*)(Khb + (size_t)kt * BK * kD) + w * 2048 + lane * 16;
        const char* gv = (const char*)(Vtb + (size_t)kt * kD * BK) + w * 2048 + lane * 16;
        char* lk = (char*)&sK[buf][0] + w * 2048;
        char* lv = (char*)&sV[buf][0] + w * 2048;
        gload_lds16(gk,        lk);
        gload_lds16(gk + 1024, lk + 1024);
        gload_lds16(gv,        lv);
        gload_lds16(gv + 1024, lv + 1024);
    };

    f32x16 o0, o1;                 // O^T accumulators: d rows 0-31 / 32-63
#pragma unroll
    for (int r = 0; r < 16; ++r) { o0[r] = 0.0f; o1[r] = 0.0f; }
    float m_i = -1e30f;
    float ll  = 0.0f;              // this lane's half of row-sum l

    stage(0, 0);
    __syncthreads();

    const int nIter = SKH / BK;   // 16
    for (int kt = 0; kt < nIter; ++kt) {
        const int buf = kt & 1;
        if (kt + 1 < nIter) stage(kt + 1, buf ^ 1);   // DMA in flight during compute

        // ---- S^T = K Q^T : two 32-key blocks, accumulate over 4 d-slices ----
        f32x16 s0, s1;
#pragma unroll
        for (int r = 0; r < 16; ++r) { s0[r] = 0.0f; s1[r] = 0.0f; }
#pragma unroll
        for (int ds = 0; ds < 4; ++ds) {
            const f16x8 kf0 = *(const f16x8*)&sK[buf][offA[ds]];
            const f16x8 kf1 = *(const f16x8*)&sK[buf][offA[ds] + 2048];
            s0 = __builtin_amdgcn_mfma_f32_32x32x16_f16(kf0, qf[ds], s0, 0, 0, 0);
            s1 = __builtin_amdgcn_mfma_f32_32x32x16_f16(kf1, qf[ds], s1, 0, 0, 0);
        }

        // ---- vf reads hoisted (overlap with softmax VALU) ----
        f16x8 vf[4][2];
#pragma unroll
        for (int s = 0; s < 4; ++s) {
            vf[s][0] = *(const f16x8*)&sV[buf][offA[s]];
            vf[s][1] = *(const f16x8*)&sV[buf][offA[s] + 2048];
        }

        // ---- in-register softmax: in-lane max tree + cross-half shfl ----
        float t[16];
#pragma unroll
        for (int r = 0; r < 16; ++r) t[r] = fmaxf(s0[r], s1[r]);
#pragma unroll
        for (int r = 0; r < 8; ++r)  t[r] = fmaxf(t[r], t[r + 8]);
#pragma unroll
        for (int r = 0; r < 4; ++r)  t[r] = fmaxf(t[r], t[r + 4]);
        float rm = fmaxf(fmaxf(t[0], t[1]), fmaxf(t[2], t[3]));
        rm = fmaxf(rm, __shfl_xor(rm, 32, 64));   // combine hi-halves of row q
        const float mnew = fmaxf(m_i, rm);

#pragma unroll
        for (int r = 0; r < 16; ++r) {
            s0[r] = __builtin_amdgcn_exp2f(s0[r] - mnew);
            s1[r] = __builtin_amdgcn_exp2f(s1[r] - mnew);
        }
        if (!__all(mnew == m_i)) {      // max moved: rescale o and ll
            const float alpha = __builtin_amdgcn_exp2f(m_i - mnew);
            ll *= alpha;
#pragma unroll
            for (int r = 0; r < 16; ++r) { o0[r] *= alpha; o1[r] *= alpha; }
        }
        m_i = mnew;

        // ---- l accumulation (in-lane tree, cross-half combine at epilogue) ----
        {
            float a0 = 0.f, a1 = 0.f, a2 = 0.f, a3 = 0.f;
#pragma unroll
            for (int r = 0; r < 16; r += 4) {
                a0 += s0[r]; a1 += s0[r + 1]; a2 += s0[r + 2]; a3 += s0[r + 3];
                a0 += s1[r]; a1 += s1[r + 1]; a2 += s1[r + 2]; a3 += s1[r + 3];
            }
            ll += (a0 + a1) + (a2 + a3);
        }

        // ---- P -> fp16 fragments (register-only, no LDS) ----
        f16x8 pa[4];
        PA_SLICE(pa[0], s0, 0);   // keys  0-15
        PA_SLICE(pa[1], s0, 8);   // keys 16-31
        PA_SLICE(pa[2], s1, 0);   // keys 32-47
        PA_SLICE(pa[3], s1, 8);   // keys 48-63

        // ---- PV: O^T += V^T P^T (q stays lane-col) ----
#pragma unroll
        for (int s = 0; s < 4; ++s) {
            o0 = __builtin_amdgcn_mfma_f32_32x32x16_f16(vf[s][0], pa[s], o0, 0, 0, 0);
            o1 = __builtin_amdgcn_mfma_f32_32x32x16_f16(vf[s][1], pa[s], o1, 0, 0, 0);
        }

        __syncthreads();   // drains prefetch DMA (vmcnt) + LDS
    }

    // ---- epilogue: o reg r holds O[d = (r&3)+8*(r>>2)+4*hi (+32 for o1)][q] ----
    _Float16* Ab = Ap + (size_t)ks * APART + ((size_t)b * kSQ + qb) * kD;
    float2* MLb = MLp + (size_t)ks * kB * kSQ + (size_t)b * kSQ + qb;
    const int q = w * 32 + l31;
    _Float16* arow = &Ab[(size_t)q * kD];
#pragma unroll
    for (int g = 0; g < 4; ++g) {
        *(f16x4*)&arow[g * 8 + hi * 4] =
            pack4(o0[4 * g], o0[4 * g + 1], o0[4 * g + 2], o0[4 * g + 3]);
        *(f16x4*)&arow[32 + g * 8 + hi * 4] =
            pack4(o1[4 * g], o1[4 * g + 1], o1[4 * g + 2], o1[4 * g + 3]);
    }
    {
        const float lf = ll + __shfl_xor(ll, 32, 64);   // both hi-halves of row
        if (hi == 0) MLb[q] = make_float2(m_i, lf);
    }
}

// ---------------- combine (exp2 domain, unchanged) ----------------
__global__ __launch_bounds__(256)
void fattn_combine(const _Float16* __restrict__ Ap,
                   const float2* __restrict__ MLp,
                   float* __restrict__ Og)
{
    const int idx = blockIdx.x * 256 + threadIdx.x;
    const int r = idx >> 4;
    const int c = (idx & 15) * 4;

    float m = -1e30f;
    float2 ml[KSPLIT];
#pragma unroll
    for (int s = 0; s < KSPLIT; ++s) {
        ml[s] = MLp[(size_t)s * kB * kSQ + r];
        m = fmaxf(m, ml[s].x);
    }
    float acc[4] = {0.f, 0.f, 0.f, 0.f};
    float lsum = 0.f;
#pragma unroll
    for (int s = 0; s < KSPLIT; ++s) {
        const float e = __builtin_amdgcn_exp2f(ml[s].x - m);
        lsum += e * ml[s].y;
        const f16x4 a = *(const f16x4*)&Ap[(size_t)s * APART + (size_t)r * kD + c];
#pragma unroll
        for (int j = 0; j < 4; ++j) acc[j] += e * (float)a[j];
    }
    const float inv = 1.0f / lsum;
    float4 res = make_float4(acc[0] * inv, acc[1] * inv, acc[2] * inv, acc[3] * inv);
    *(float4*)&Og[(size_t)r * kD + c] = res;
}

extern "C" void kernel_launch(void* const* d_in, const int* in_sizes, int n_in,
                              void* d_out, int out_size, void* d_ws, size_t ws_size,
                              hipStream_t stream) {
    const float* Q    = (const float*)d_in[0];
    const float* K    = (const float*)d_in[1];
    const float* V    = (const float*)d_in[2];
    const float* sdiv = (const float*)d_in[4];
    float* O = (float*)d_out;

    // workspace: Kh 4MB | Vt 4MB | Ap fp16 16.8MB | MLp 1MB
    _Float16* Kh  = (_Float16*)d_ws;
    _Float16* Vt  = Kh + (size_t)kB * kSK * kD;
    _Float16* Ap  = Vt + (size_t)kB * kSK * kD;
    float2*   MLp = (float2*)(Ap + (size_t)KSPLIT * APART);

    fattn_prepass<<<dim3(kSK / BK, kB), dim3(256), 0, stream>>>(K, V, Kh, Vt);
    fattn_partial<<<dim3((kSQ / BQ) * kB * KSPLIT), dim3(256), 0, stream>>>(Q, Kh, Vt, sdiv, Ap, MLp);
    fattn_combine<<<dim3(kB * kSQ * kD / (256 * 4)), dim3(256), 0, stream>>>(Ap, MLp, O);
}

// Round 3
// 134.955 us; speedup vs baseline: 1.0594x; 1.0594x over previous
//
#include <hip/hip_runtime.h>

// Flash attention forward, fp32 in/out, fp16 MFMA compute.
// B=8, SQ=SK=4096, D=64. scores = (Q/x5) K^T ; softmax ; O = P V.
// R15 = R14 (32x32x16 swapped-QK^T, in-register softmax, permlane P
// redistribution) + restored M-tile amortization + defer-max.
// R14 post-mortem: removing sP was offset by losing R12's MT=4 kf/vf
// amortization (LDS bytes/q unchanged at 0.5KB), conflicts doubled, FETCH
// +38% (2x blocks per K/V stream). Occupancy gain was costless (R11).
// R15: MT=2, BQ=256 (4 waves x 2 tiles of 32 q). vf read once per kt shared
// across both M-tiles; kf re-read per tile -> 24 b128/wave-kt over 64 q =
// 0.375 KB/q (-25% vs R12/R14). Stage DMA, barriers, acc-init per output
// halve vs R14. T13 defer-max (THR=11.5 exp2-domain = 8 nats): skip
// o-rescale while tile max grows < THR. Ap now stored NORMALIZED (O/l) so
// deferred-scale P (<=2^11.5) can't overflow fp16; combine weights e*l
// (algebraically identical). launch_bounds (256,2): softmax state stays in
// VGPRs, no accvgpr churn. Grid 512 = 2 blocks/CU.

typedef _Float16 f16x8 __attribute__((ext_vector_type(8)));
typedef _Float16 f16x4 __attribute__((ext_vector_type(4)));
typedef __fp16   h16x2 __attribute__((ext_vector_type(2)));
typedef float    f32x4 __attribute__((ext_vector_type(4)));
typedef float    f32x16 __attribute__((ext_vector_type(16)));

constexpr int kB  = 8;
constexpr int kSQ = 4096;
constexpr int kSK = 4096;
constexpr int kD  = 64;
constexpr int KSPLIT = 4;
constexpr int SKH = kSK / KSPLIT;     // 1024 keys per split
constexpr int BQ  = 256;              // 4 waves x 2 M-tiles x 32 Q rows
constexpr int MT  = 2;
constexpr int BK  = 64;
constexpr size_t APART = (size_t)kB * kSQ * kD;
constexpr float kLog2e = 1.44269504088896340736f;
constexpr float kDeferThr = 11.5f;    // exp2-domain (~8 nats); P <= 2^11.5

static __device__ __forceinline__ f16x4 pack4(float a, float b, float c, float d) {
    h16x2 p0 = __builtin_amdgcn_cvt_pkrtz(a, b);
    h16x2 p1 = __builtin_amdgcn_cvt_pkrtz(c, d);
    f16x4 r;
    r[0] = (_Float16)p0[0]; r[1] = (_Float16)p0[1];
    r[2] = (_Float16)p1[0]; r[3] = (_Float16)p1[1];
    return r;
}
static __device__ __forceinline__ f16x8 pack8(const float4& a, const float4& c) {
    f16x4 lo = pack4(a.x, a.y, a.z, a.w);
    f16x4 hi = pack4(c.x, c.y, c.z, c.w);
    f16x8 f;
    f[0] = lo[0]; f[1] = lo[1]; f[2] = lo[2]; f[3] = lo[3];
    f[4] = hi[0]; f[5] = hi[1]; f[6] = hi[2]; f[7] = hi[3];
    return f;
}
static __device__ __forceinline__ unsigned pkrtz_u(float a, float b) {
    union { h16x2 h; unsigned u; } cv;
    cv.h = __builtin_amdgcn_cvt_pkrtz(a, b);
    return cv.u;
}

typedef const __attribute__((address_space(1))) unsigned int* gu32p;
typedef __attribute__((address_space(3))) unsigned int* lu32p;
static __device__ __forceinline__ void gload_lds16(const void* g, void* l) {
    __builtin_amdgcn_global_load_lds((gu32p)g, (lu32p)l, 16, 0, 0);
}

// P slice (8 regs of one 32-key C-block) -> f16x8 PV fragment.
// C/D rows: key = (r&3)+8*(r>>2)+4*hi. Pair cvtpk(p[2i],p[2i+1]) with
// cvtpk(p[2i+4],p[2i+5]); one permlane32_swap fills two output words.
#define PA_SLICE(dst, sv, rb) do {                                          \
    unsigned c0 = pkrtz_u((sv)[(rb)+0], (sv)[(rb)+1]);                      \
    unsigned c1 = pkrtz_u((sv)[(rb)+2], (sv)[(rb)+3]);                      \
    unsigned c2 = pkrtz_u((sv)[(rb)+4], (sv)[(rb)+5]);                      \
    unsigned c3 = pkrtz_u((sv)[(rb)+6], (sv)[(rb)+7]);                      \
    auto r02 = __builtin_amdgcn_permlane32_swap(c0, c2, false, false);      \
    auto r13 = __builtin_amdgcn_permlane32_swap(c1, c3, false, false);      \
    union { unsigned u[4]; f16x8 v; } _r;                                   \
    _r.u[0] = r02[0]; _r.u[1] = r13[0]; _r.u[2] = r02[1]; _r.u[3] = r13[1]; \
    dst = _r.v;                                                             \
} while (0)

// ---------------- pre-pass: K -> Kh (swizzled fp16), V -> Vt (transposed,
// tiled, swizzled fp16). Kh[b][k][blk fb^(k&7)][8]; Vt[b][kt][f][blk kb^(f&7)][8].
__global__ __launch_bounds__(256, 2)
void fattn_prepass(const float* __restrict__ Kg,
                   const float* __restrict__ Vg,
                   _Float16* __restrict__ Kh,
                   _Float16* __restrict__ Vt)
{
    __shared__ _Float16 tr[kD][BK];

    const int tid = threadIdx.x;
    const int kt  = blockIdx.x;
    const int b   = blockIdx.y;

    const int k = tid >> 2;
    const int p = tid & 3;
    const int gk = kt * BK + k;

    {
        const float* src = Kg + ((size_t)b * kSK + gk) * kD + p * 16;
        const float4 a0 = *(const float4*)(src + 0);
        const float4 a1 = *(const float4*)(src + 4);
        const float4 a2 = *(const float4*)(src + 8);
        const float4 a3 = *(const float4*)(src + 12);
        _Float16* dst = Kh + ((size_t)b * kSK + gk) * kD;
        const int fb0 = 2 * p, fb1 = 2 * p + 1;
        *(f16x8*)&dst[(fb0 ^ (gk & 7)) * 8] = pack8(a0, a1);
        *(f16x8*)&dst[(fb1 ^ (gk & 7)) * 8] = pack8(a2, a3);
    }
    {
        const float* src = Vg + ((size_t)b * kSK + gk) * kD + p * 16;
        const float4 a0 = *(const float4*)(src + 0);
        const float4 a1 = *(const float4*)(src + 4);
        const float4 a2 = *(const float4*)(src + 8);
        const float4 a3 = *(const float4*)(src + 12);
        const float v[16] = {a0.x,a0.y,a0.z,a0.w, a1.x,a1.y,a1.z,a1.w,
                             a2.x,a2.y,a2.z,a2.w, a3.x,a3.y,a3.z,a3.w};
#pragma unroll
        for (int j = 0; j < 16; ++j)
            tr[p * 16 + j][k] = (_Float16)v[j];
    }
    __syncthreads();
    {
        const int f  = tid >> 2;
        const int p2 = tid & 3;
        const f16x8 b0 = *(const f16x8*)&tr[f][p2 * 16 + 0];
        const f16x8 b1 = *(const f16x8*)&tr[f][p2 * 16 + 8];
        _Float16* dst = Vt + (((size_t)b * 64 + kt) * kD + f) * BK;
        const int kb0 = 2 * p2, kb1 = 2 * p2 + 1;
        *(f16x8*)&dst[(kb0 ^ (f & 7)) * 8] = b0;
        *(f16x8*)&dst[(kb1 ^ (f & 7)) * 8] = b1;
    }
}

// ---------------- main partial kernel (32x32x16 MFMA, MT=2) ----------------
__global__ __launch_bounds__(256, 2)
void fattn_partial(const float* __restrict__ Qg,
                   const _Float16* __restrict__ Kh,
                   const _Float16* __restrict__ Vt,
                   const float* __restrict__ sdiv,
                   _Float16* __restrict__ Ap,   // [KSPLIT][B][SQ][D] NORMALIZED (O/l)
                   float2* __restrict__ MLp)    // [KSPLIT][B][SQ] (m,l) exp2-domain
{
    __shared__ __align__(16) _Float16 sK[2][BK * kD];   // 16 KB
    __shared__ __align__(16) _Float16 sV[2][kD * BK];   // 16 KB

    const int tid  = threadIdx.x;
    const int w    = tid >> 6;
    const int lane = tid & 63;
    const int l31  = lane & 31;
    const int hi   = lane >> 5;

    // XCD-affine decode: flat = c + 32*q; c = (b,ks); all 16 q-blocks of one
    // K/V stream share an XCD (flat%8 invariant across q).
    const int flat = blockIdx.x;
    const int c    = flat & 31;
    const int qi   = flat >> 5;
    const int b    = c >> 2;      // KSPLIT = 4
    const int ks   = c & 3;
    const int qb   = qi * BQ;

    const float qscale = kLog2e / sdiv[0];   // exp2 domain

    const float* Qb = Qg + ((size_t)b * kSQ + qb) * kD;
    const _Float16* Khb = Kh + ((size_t)b * kSK + (size_t)ks * SKH) * kD;
    const _Float16* Vtb = Vt + (((size_t)b * 64 + (size_t)ks * (SKH / BK)) * kD) * BK;

    // ---- Q fragments: qf[mt][ds][j] = Q[q][ds*16 + hi*8 + j]*qscale,
    //      q = qb + w*64 + mt*32 + l31 (lane-col of all MFMAs) ----
    f16x8 qf[MT][4];
#pragma unroll
    for (int mt = 0; mt < MT; ++mt) {
        const float* qrow = Qb + (size_t)(w * 64 + mt * 32 + l31) * kD;
#pragma unroll
        for (int ds = 0; ds < 4; ++ds) {
            const float4 a  = *(const float4*)(qrow + ds * 16 + hi * 8);
            const float4 cc = *(const float4*)(qrow + ds * 16 + hi * 8 + 4);
            float4 as = make_float4(a.x * qscale, a.y * qscale, a.z * qscale, a.w * qscale);
            float4 cs = make_float4(cc.x * qscale, cc.y * qscale, cc.z * qscale, cc.w * qscale);
            qf[mt][ds] = pack8(as, cs);
        }
    }

    // Swizzled LDS fragment offsets (halves); identical pattern for K and V:
    // row = l31 (+32 for second block), 16B slot = (2*i + hi) ^ (row & 7).
    int offA[4];
#pragma unroll
    for (int i = 0; i < 4; ++i)
        offA[i] = l31 * 64 + (((2 * i + hi) ^ (l31 & 7)) * 8);

    // ---- async staging: 4 global_load_lds per wave ----
    auto stage = [&](int kt, int buf) {
        const char* gk = (const char*)(Khb + (size_t)kt * BK * kD) + w * 2048 + lane * 16;
        const char* gv = (const char*)(Vtb + (size_t)kt * kD * BK) + w * 2048 + lane * 16;
        char* lk = (char*)&sK[buf][0] + w * 2048;
        char* lv = (char*)&sV[buf][0] + w * 2048;
        gload_lds16(gk,        lk);
        gload_lds16(gk + 1024, lk + 1024);
        gload_lds16(gv,        lv);
        gload_lds16(gv + 1024, lv + 1024);
    };

    f32x16 oL[MT], oH[MT];         // O^T accumulators: d rows 0-31 / 32-63
    float m_i[MT], ll[MT];
#pragma unroll
    for (int mt = 0; mt < MT; ++mt) {
        m_i[mt] = -1e30f; ll[mt] = 0.0f;
#pragma unroll
        for (int r = 0; r < 16; ++r) { oL[mt][r] = 0.0f; oH[mt][r] = 0.0f; }
    }

    stage(0, 0);
    __syncthreads();

    const int nIter = SKH / BK;   // 16
    for (int kt = 0; kt < nIter; ++kt) {
        const int buf = kt & 1;
        if (kt + 1 < nIter) stage(kt + 1, buf ^ 1);   // DMA in flight during compute

        // ---- vf reads: ONCE per kt, shared by both M-tiles ----
        f16x8 vf[4][2];
#pragma unroll
        for (int s = 0; s < 4; ++s) {
            vf[s][0] = *(const f16x8*)&sV[buf][offA[s]];
            vf[s][1] = *(const f16x8*)&sV[buf][offA[s] + 2048];
        }

#pragma unroll
        for (int mt = 0; mt < MT; ++mt) {
            // ---- S^T = K Q^T : two 32-key blocks, accumulate over d-slices ----
            f32x16 s0, s1;
#pragma unroll
            for (int r = 0; r < 16; ++r) { s0[r] = 0.0f; s1[r] = 0.0f; }
#pragma unroll
            for (int ds = 0; ds < 4; ++ds) {
                const f16x8 kf0 = *(const f16x8*)&sK[buf][offA[ds]];
                const f16x8 kf1 = *(const f16x8*)&sK[buf][offA[ds] + 2048];
                s0 = __builtin_amdgcn_mfma_f32_32x32x16_f16(kf0, qf[mt][ds], s0, 0, 0, 0);
                s1 = __builtin_amdgcn_mfma_f32_32x32x16_f16(kf1, qf[mt][ds], s1, 0, 0, 0);
            }

            // ---- in-register softmax: in-lane max tree + cross-half shfl ----
            float t[16];
#pragma unroll
            for (int r = 0; r < 16; ++r) t[r] = fmaxf(s0[r], s1[r]);
#pragma unroll
            for (int r = 0; r < 8; ++r)  t[r] = fmaxf(t[r], t[r + 8]);
#pragma unroll
            for (int r = 0; r < 4; ++r)  t[r] = fmaxf(t[r], t[r + 4]);
            float rm = fmaxf(fmaxf(t[0], t[1]), fmaxf(t[2], t[3]));
            rm = fmaxf(rm, __shfl_xor(rm, 32, 64));   // combine hi-halves of row q

            // T13 defer-max: only rescale when some row's max grew > THR
            if (!__all(rm <= m_i[mt] + kDeferThr)) {
                const float mnew  = fmaxf(m_i[mt], rm);
                const float alpha = __builtin_amdgcn_exp2f(m_i[mt] - mnew);
                ll[mt] *= alpha;
#pragma unroll
                for (int r = 0; r < 16; ++r) { oL[mt][r] *= alpha; oH[mt][r] *= alpha; }
                m_i[mt] = mnew;
            }

#pragma unroll
            for (int r = 0; r < 16; ++r) {
                s0[r] = __builtin_amdgcn_exp2f(s0[r] - m_i[mt]);
                s1[r] = __builtin_amdgcn_exp2f(s1[r] - m_i[mt]);
            }

            // ---- l accumulation (in-lane tree; cross-half at epilogue) ----
            {
                float a0 = 0.f, a1 = 0.f, a2 = 0.f, a3 = 0.f;
#pragma unroll
                for (int r = 0; r < 16; r += 4) {
                    a0 += s0[r]; a1 += s0[r + 1]; a2 += s0[r + 2]; a3 += s0[r + 3];
                    a0 += s1[r]; a1 += s1[r + 1]; a2 += s1[r + 2]; a3 += s1[r + 3];
                }
                ll[mt] += (a0 + a1) + (a2 + a3);
            }

            // ---- P -> fp16 fragments (register-only, no LDS) ----
            f16x8 pa[4];
            PA_SLICE(pa[0], s0, 0);   // keys  0-15
            PA_SLICE(pa[1], s0, 8);   // keys 16-31
            PA_SLICE(pa[2], s1, 0);   // keys 32-47
            PA_SLICE(pa[3], s1, 8);   // keys 48-63

            // ---- PV: O^T += V^T P^T (q stays lane-col) ----
#pragma unroll
            for (int s = 0; s < 4; ++s) {
                oL[mt] = __builtin_amdgcn_mfma_f32_32x32x16_f16(vf[s][0], pa[s], oL[mt], 0, 0, 0);
                oH[mt] = __builtin_amdgcn_mfma_f32_32x32x16_f16(vf[s][1], pa[s], oH[mt], 0, 0, 0);
            }
        }

        __syncthreads();   // drains prefetch DMA (vmcnt) + LDS
    }

    // ---- epilogue: o reg r holds O[d = (r&3)+8*(r>>2)+4*hi (+32 for oH)][q].
    //      Store Ap NORMALIZED by 1/l (fp16-safe under defer-max). ----
    _Float16* Ab = Ap + (size_t)ks * APART + ((size_t)b * kSQ + qb) * kD;
    float2* MLb = MLp + (size_t)ks * kB * kSQ + (size_t)b * kSQ + qb;
#pragma unroll
    for (int mt = 0; mt < MT; ++mt) {
        const int q = w * 64 + mt * 32 + l31;
        const float lf = ll[mt] + __shfl_xor(ll[mt], 32, 64);   // full row sum
        const float inv = 1.0f / lf;
        _Float16* arow = &Ab[(size_t)q * kD];
#pragma unroll
        for (int g = 0; g < 4; ++g) {
            *(f16x4*)&arow[g * 8 + hi * 4] =
                pack4(oL[mt][4 * g] * inv, oL[mt][4 * g + 1] * inv,
                      oL[mt][4 * g + 2] * inv, oL[mt][4 * g + 3] * inv);
            *(f16x4*)&arow[32 + g * 8 + hi * 4] =
                pack4(oH[mt][4 * g] * inv, oH[mt][4 * g + 1] * inv,
                      oH[mt][4 * g + 2] * inv, oH[mt][4 * g + 3] * inv);
        }
        if (hi == 0) MLb[q] = make_float2(m_i[mt], lf);
    }
}

// ---------------- combine (exp2 domain; Ap normalized, weight = e*l) ----------------
__global__ __launch_bounds__(256)
void fattn_combine(const _Float16* __restrict__ Ap,
                   const float2* __restrict__ MLp,
                   float* __restrict__ Og)
{
    const int idx = blockIdx.x * 256 + threadIdx.x;
    const int r = idx >> 4;
    const int c = (idx & 15) * 4;

    float m = -1e30f;
    float2 ml[KSPLIT];
#pragma unroll
    for (int s = 0; s < KSPLIT; ++s) {
        ml[s] = MLp[(size_t)s * kB * kSQ + r];
        m = fmaxf(m, ml[s].x);
    }
    float acc[4] = {0.f, 0.f, 0.f, 0.f};
    float lsum = 0.f;
#pragma unroll
    for (int s = 0; s < KSPLIT; ++s) {
        const float wgt = __builtin_amdgcn_exp2f(ml[s].x - m) * ml[s].y;
        lsum += wgt;
        const f16x4 a = *(const f16x4*)&Ap[(size_t)s * APART + (size_t)r * kD + c];
#pragma unroll
        for (int j = 0; j < 4; ++j) acc[j] += wgt * (float)a[j];
    }
    const float inv = 1.0f / lsum;
    float4 res = make_float4(acc[0] * inv, acc[1] * inv, acc[2] * inv, acc[3] * inv);
    *(float4*)&Og[(size_t)r * kD + c] = res;
}

extern "C" void kernel_launch(void* const* d_in, const int* in_sizes, int n_in,
                              void* d_out, int out_size, void* d_ws, size_t ws_size,
                              hipStream_t stream) {
    const float* Q    = (const float*)d_in[0];
    const float* K    = (const float*)d_in[1];
    const float* V    = (const float*)d_in[2];
    const float* sdiv = (const float*)d_in[4];
    float* O = (float*)d_out;

    // workspace: Kh 4MB | Vt 4MB | Ap fp16 16.8MB | MLp 1MB
    _Float16* Kh  = (_Float16*)d_ws;
    _Float16* Vt  = Kh + (size_t)kB * kSK * kD;
    _Float16* Ap  = Vt + (size_t)kB * kSK * kD;
    float2*   MLp = (float2*)(Ap + (size_t)KSPLIT * APART);

    fattn_prepass<<<dim3(kSK / BK, kB), dim3(256), 0, stream>>>(K, V, Kh, Vt);
    fattn_partial<<<dim3((kSQ / BQ) * kB * KSPLIT), dim3(256), 0, stream>>>(Q, Kh, Vt, sdiv, Ap, MLp);
    fattn_combine<<<dim3(kB * kSQ * kD / (256 * 4)), dim3(256), 0, stream>>>(Ap, MLp, O);
}

// Round 6
// 133.808 us; speedup vs baseline: 1.0685x; 1.0086x over previous
//
#include <hip/hip_runtime.h>

// Flash attention forward, fp32 in/out, fp16 MFMA compute.
// B=8, SQ=SK=4096, D=64. scores = (Q/x5) K^T ; softmax ; O = P V.
// R19 = R16 resubmitted verbatim (R4/R5 benches were infra failures:
// "container failed twice", "Trio nursery ExceptionGroup" — no kernel signal).
// R16 = R15 + chain/work surgery. R15 post-mortem: 63.7us == R12's 63.5 with
// nothing saturated (Mfma 22%, VALU 44%, DS ~30%, HBM 7.6%) -> latency/
// VALU-work bound at 2 waves/SIMD. Changes:
//  - kf read ONCE per kt (was per M-tile): 24 -> 16 b128/wave-kt.
//  - QK phase-split: all 16 QK MFMAs clustered (mt1 QK no longer behind mt0
//    softmax), s_setprio(1) around MFMA clusters (T5).
//  - fused l via ones-MFMA (R12 trick, 32x32 form): deletes ~70 VALU adds/kt
//    AND the epilogue cross-half shfl (MFMA K-dim sums both hi-halves).
//  - cross-half row-max via permlane32_swap BUILTIN + fmax (VALU ~4cy)
//    replacing __shfl_xor (DS ~50cy) inside the serial max chain.
// Kept: 32x32x16 swapped QK^T (q = lane&31), in-register softmax, permlane
// P redistribution, MT=2 / BQ=256, defer-max (THR=11.5 exp2-domain),
// normalized Ap (fp16-safe), dbuf global_load_lds staging, XCD-affine grid.

typedef _Float16 f16x8 __attribute__((ext_vector_type(8)));
typedef _Float16 f16x4 __attribute__((ext_vector_type(4)));
typedef __fp16   h16x2 __attribute__((ext_vector_type(2)));
typedef float    f32x4 __attribute__((ext_vector_type(4)));
typedef float    f32x16 __attribute__((ext_vector_type(16)));

constexpr int kB  = 8;
constexpr int kSQ = 4096;
constexpr int kSK = 4096;
constexpr int kD  = 64;
constexpr int KSPLIT = 4;
constexpr int SKH = kSK / KSPLIT;     // 1024 keys per split
constexpr int BQ  = 256;              // 4 waves x 2 M-tiles x 32 Q rows
constexpr int MT  = 2;
constexpr int BK  = 64;
constexpr size_t APART = (size_t)kB * kSQ * kD;
constexpr float kLog2e = 1.44269504088896340736f;
constexpr float kDeferThr = 11.5f;    // exp2-domain (~8 nats); P <= 2^11.5

static __device__ __forceinline__ f16x4 pack4(float a, float b, float c, float d) {
    h16x2 p0 = __builtin_amdgcn_cvt_pkrtz(a, b);
    h16x2 p1 = __builtin_amdgcn_cvt_pkrtz(c, d);
    f16x4 r;
    r[0] = (_Float16)p0[0]; r[1] = (_Float16)p0[1];
    r[2] = (_Float16)p1[0]; r[3] = (_Float16)p1[1];
    return r;
}
static __device__ __forceinline__ f16x8 pack8(const float4& a, const float4& c) {
    f16x4 lo = pack4(a.x, a.y, a.z, a.w);
    f16x4 hi = pack4(c.x, c.y, c.z, c.w);
    f16x8 f;
    f[0] = lo[0]; f[1] = lo[1]; f[2] = lo[2]; f[3] = lo[3];
    f[4] = hi[0]; f[5] = hi[1]; f[6] = hi[2]; f[7] = hi[3];
    return f;
}
static __device__ __forceinline__ unsigned pkrtz_u(float a, float b) {
    union { h16x2 h; unsigned u; } cv;
    cv.h = __builtin_amdgcn_cvt_pkrtz(a, b);
    return cv.u;
}
static __device__ __forceinline__ float xhalf_max(float x) {
    // max(x[lane], x[lane^32]) in every lane, VALU-only.
    union { float f; unsigned u; } uv; uv.f = x;
    auto pr = __builtin_amdgcn_permlane32_swap(uv.u, uv.u, false, false);
    union { unsigned u; float f; } r0, r1;
    r0.u = pr[0]; r1.u = pr[1];
    return fmaxf(r0.f, r1.f);
}

typedef const __attribute__((address_space(1))) unsigned int* gu32p;
typedef __attribute__((address_space(3))) unsigned int* lu32p;
static __device__ __forceinline__ void gload_lds16(const void* g, void* l) {
    __builtin_amdgcn_global_load_lds((gu32p)g, (lu32p)l, 16, 0, 0);
}

// P slice (8 regs of one 32-key C-block) -> f16x8 PV fragment.
// C/D rows: key = (r&3)+8*(r>>2)+4*hi. Pair cvtpk(p[2i],p[2i+1]) with
// cvtpk(p[2i+4],p[2i+5]); one permlane32_swap fills two output words.
#define PA_SLICE(dst, sv, rb) do {                                          \
    unsigned c0 = pkrtz_u((sv)[(rb)+0], (sv)[(rb)+1]);                      \
    unsigned c1 = pkrtz_u((sv)[(rb)+2], (sv)[(rb)+3]);                      \
    unsigned c2 = pkrtz_u((sv)[(rb)+4], (sv)[(rb)+5]);                      \
    unsigned c3 = pkrtz_u((sv)[(rb)+6], (sv)[(rb)+7]);                      \
    auto r02 = __builtin_amdgcn_permlane32_swap(c0, c2, false, false);      \
    auto r13 = __builtin_amdgcn_permlane32_swap(c1, c3, false, false);      \
    union { unsigned u[4]; f16x8 v; } _r;                                   \
    _r.u[0] = r02[0]; _r.u[1] = r13[0]; _r.u[2] = r02[1]; _r.u[3] = r13[1]; \
    dst = _r.v;                                                             \
} while (0)

// ---------------- pre-pass: K -> Kh (swizzled fp16), V -> Vt (transposed,
// tiled, swizzled fp16). Kh[b][k][blk fb^(k&7)][8]; Vt[b][kt][f][blk kb^(f&7)][8].
__global__ __launch_bounds__(256, 2)
void fattn_prepass(const float* __restrict__ Kg,
                   const float* __restrict__ Vg,
                   _Float16* __restrict__ Kh,
                   _Float16* __restrict__ Vt)
{
    __shared__ _Float16 tr[kD][BK];

    const int tid = threadIdx.x;
    const int kt  = blockIdx.x;
    const int b   = blockIdx.y;

    const int k = tid >> 2;
    const int p = tid & 3;
    const int gk = kt * BK + k;

    {
        const float* src = Kg + ((size_t)b * kSK + gk) * kD + p * 16;
        const float4 a0 = *(const float4*)(src + 0);
        const float4 a1 = *(const float4*)(src + 4);
        const float4 a2 = *(const float4*)(src + 8);
        const float4 a3 = *(const float4*)(src + 12);
        _Float16* dst = Kh + ((size_t)b * kSK + gk) * kD;
        const int fb0 = 2 * p, fb1 = 2 * p + 1;
        *(f16x8*)&dst[(fb0 ^ (gk & 7)) * 8] = pack8(a0, a1);
        *(f16x8*)&dst[(fb1 ^ (gk & 7)) * 8] = pack8(a2, a3);
    }
    {
        const float* src = Vg + ((size_t)b * kSK + gk) * kD + p * 16;
        const float4 a0 = *(const float4*)(src + 0);
        const float4 a1 = *(const float4*)(src + 4);
        const float4 a2 = *(const float4*)(src + 8);
        const float4 a3 = *(const float4*)(src + 12);
        const float v[16] = {a0.x,a0.y,a0.z,a0.w, a1.x,a1.y,a1.z,a1.w,
                             a2.x,a2.y,a2.z,a2.w, a3.x,a3.y,a3.z,a3.w};
#pragma unroll
        for (int j = 0; j < 16; ++j)
            tr[p * 16 + j][k] = (_Float16)v[j];
    }
    __syncthreads();
    {
        const int f  = tid >> 2;
        const int p2 = tid & 3;
        const f16x8 b0 = *(const f16x8*)&tr[f][p2 * 16 + 0];
        const f16x8 b1 = *(const f16x8*)&tr[f][p2 * 16 + 8];
        _Float16* dst = Vt + (((size_t)b * 64 + kt) * kD + f) * BK;
        const int kb0 = 2 * p2, kb1 = 2 * p2 + 1;
        *(f16x8*)&dst[(kb0 ^ (f & 7)) * 8] = b0;
        *(f16x8*)&dst[(kb1 ^ (f & 7)) * 8] = b1;
    }
}

// ---------------- main partial kernel (32x32x16 MFMA, MT=2, phase-split) ----------------
__global__ __launch_bounds__(256, 2)
void fattn_partial(const float* __restrict__ Qg,
                   const _Float16* __restrict__ Kh,
                   const _Float16* __restrict__ Vt,
                   const float* __restrict__ sdiv,
                   _Float16* __restrict__ Ap,   // [KSPLIT][B][SQ][D] NORMALIZED (O/l)
                   float2* __restrict__ MLp)    // [KSPLIT][B][SQ] (m,l) exp2-domain
{
    __shared__ __align__(16) _Float16 sK[2][BK * kD];   // 16 KB
    __shared__ __align__(16) _Float16 sV[2][kD * BK];   // 16 KB

    const int tid  = threadIdx.x;
    const int w    = tid >> 6;
    const int lane = tid & 63;
    const int l31  = lane & 31;
    const int hi   = lane >> 5;

    // XCD-affine decode: flat = c + 32*q; c = (b,ks); all 16 q-blocks of one
    // K/V stream share an XCD (flat%8 invariant across q).
    const int flat = blockIdx.x;
    const int c    = flat & 31;
    const int qi   = flat >> 5;
    const int b    = c >> 2;      // KSPLIT = 4
    const int ks   = c & 3;
    const int qb   = qi * BQ;

    const float qscale = kLog2e / sdiv[0];   // exp2 domain

    const float* Qb = Qg + ((size_t)b * kSQ + qb) * kD;
    const _Float16* Khb = Kh + ((size_t)b * kSK + (size_t)ks * SKH) * kD;
    const _Float16* Vtb = Vt + (((size_t)b * 64 + (size_t)ks * (SKH / BK)) * kD) * BK;

    // ---- Q fragments: qf[mt][ds][j] = Q[q][ds*16 + hi*8 + j]*qscale,
    //      q = qb + w*64 + mt*32 + l31 (lane-col of all MFMAs) ----
    f16x8 qf[MT][4];
#pragma unroll
    for (int mt = 0; mt < MT; ++mt) {
        const float* qrow = Qb + (size_t)(w * 64 + mt * 32 + l31) * kD;
#pragma unroll
        for (int ds = 0; ds < 4; ++ds) {
            const float4 a  = *(const float4*)(qrow + ds * 16 + hi * 8);
            const float4 cc = *(const float4*)(qrow + ds * 16 + hi * 8 + 4);
            float4 as = make_float4(a.x * qscale, a.y * qscale, a.z * qscale, a.w * qscale);
            float4 cs = make_float4(cc.x * qscale, cc.y * qscale, cc.z * qscale, cc.w * qscale);
            qf[mt][ds] = pack8(as, cs);
        }
    }

    // ones A-fragment for the fused-l MFMA
    f16x8 ones;
#pragma unroll
    for (int j = 0; j < 8; ++j) ones[j] = (_Float16)1.0f;

    // Swizzled LDS fragment offsets (halves); identical pattern for K and V:
    // row = l31 (+32 for second block), 16B slot = (2*i + hi) ^ (row & 7).
    int offA[4];
#pragma unroll
    for (int i = 0; i < 4; ++i)
        offA[i] = l31 * 64 + (((2 * i + hi) ^ (l31 & 7)) * 8);

    // ---- async staging: 4 global_load_lds per wave ----
    auto stage = [&](int kt, int buf) {
        const char* gk = (const char*)(Khb + (size_t)kt * BK * kD) + w * 2048 + lane * 16;
        const char* gv = (const char*)(Vtb + (size_t)kt * kD * BK) + w * 2048 + lane * 16;
        char* lk = (char*)&sK[buf][0] + w * 2048;
        char* lv = (char*)&sV[buf][0] + w * 2048;
        gload_lds16(gk,        lk);
        gload_lds16(gk + 1024, lk + 1024);
        gload_lds16(gv,        lv);
        gload_lds16(gv + 1024, lv + 1024);
    };

    f32x16 oL[MT], oH[MT];         // O^T accumulators: d rows 0-31 / 32-63
    f32x16 ol[MT];                 // fused-l accumulator (only [0] consumed)
    float m_i[MT];
#pragma unroll
    for (int mt = 0; mt < MT; ++mt) {
        m_i[mt] = -1e30f;
        ol[mt][0] = 0.0f;
#pragma unroll
        for (int r = 0; r < 16; ++r) { oL[mt][r] = 0.0f; oH[mt][r] = 0.0f; ol[mt][r] = 0.0f; }
    }

    stage(0, 0);
    __syncthreads();

    const int nIter = SKH / BK;   // 16
    for (int kt = 0; kt < nIter; ++kt) {
        const int buf = kt & 1;
        if (kt + 1 < nIter) stage(kt + 1, buf ^ 1);   // DMA in flight during compute

        // ---- kf reads: ONCE per kt, shared by both M-tiles ----
        f16x8 kf0[4], kf1[4];
#pragma unroll
        for (int ds = 0; ds < 4; ++ds) {
            kf0[ds] = *(const f16x8*)&sK[buf][offA[ds]];
            kf1[ds] = *(const f16x8*)&sK[buf][offA[ds] + 2048];
        }

        // ---- QK phase: all 16 MFMAs clustered (both M-tiles) ----
        f32x16 s0[MT], s1[MT];
#pragma unroll
        for (int mt = 0; mt < MT; ++mt)
#pragma unroll
            for (int r = 0; r < 16; ++r) { s0[mt][r] = 0.0f; s1[mt][r] = 0.0f; }

        __builtin_amdgcn_s_setprio(1);
#pragma unroll
        for (int ds = 0; ds < 4; ++ds)
#pragma unroll
            for (int mt = 0; mt < MT; ++mt) {
                s0[mt] = __builtin_amdgcn_mfma_f32_32x32x16_f16(kf0[ds], qf[mt][ds], s0[mt], 0, 0, 0);
                s1[mt] = __builtin_amdgcn_mfma_f32_32x32x16_f16(kf1[ds], qf[mt][ds], s1[mt], 0, 0, 0);
            }
        __builtin_amdgcn_s_setprio(0);

        // ---- vf reads (DS overlaps softmax VALU) ----
        f16x8 vf[4][2];
#pragma unroll
        for (int s = 0; s < 4; ++s) {
            vf[s][0] = *(const f16x8*)&sV[buf][offA[s]];
            vf[s][1] = *(const f16x8*)&sV[buf][offA[s] + 2048];
        }

#pragma unroll
        for (int mt = 0; mt < MT; ++mt) {
            // ---- in-register softmax: in-lane max tree + VALU cross-half ----
            float t[16];
#pragma unroll
            for (int r = 0; r < 16; ++r) t[r] = fmaxf(s0[mt][r], s1[mt][r]);
#pragma unroll
            for (int r = 0; r < 8; ++r)  t[r] = fmaxf(t[r], t[r + 8]);
#pragma unroll
            for (int r = 0; r < 4; ++r)  t[r] = fmaxf(t[r], t[r + 4]);
            float rm = fmaxf(fmaxf(t[0], t[1]), fmaxf(t[2], t[3]));
            rm = xhalf_max(rm);     // combine hi-halves of row q (permlane, VALU)

            // T13 defer-max: only rescale when some row's max grew > THR
            if (!__all(rm <= m_i[mt] + kDeferThr)) {
                const float mnew  = fmaxf(m_i[mt], rm);
                const float alpha = __builtin_amdgcn_exp2f(m_i[mt] - mnew);
                ol[mt][0] *= alpha;
#pragma unroll
                for (int r = 0; r < 16; ++r) { oL[mt][r] *= alpha; oH[mt][r] *= alpha; }
                m_i[mt] = mnew;
            }

#pragma unroll
            for (int r = 0; r < 16; ++r) {
                s0[mt][r] = __builtin_amdgcn_exp2f(s0[mt][r] - m_i[mt]);
                s1[mt][r] = __builtin_amdgcn_exp2f(s1[mt][r] - m_i[mt]);
            }

            // ---- P -> fp16 fragments (register-only, no LDS) ----
            f16x8 pa[4];
            PA_SLICE(pa[0], s0[mt], 0);   // keys  0-15
            PA_SLICE(pa[1], s0[mt], 8);   // keys 16-31
            PA_SLICE(pa[2], s1[mt], 0);   // keys 32-47
            PA_SLICE(pa[3], s1[mt], 8);   // keys 48-63

            // ---- PV + fused l: O^T += V^T P^T ; l += 1^T P^T ----
            __builtin_amdgcn_s_setprio(1);
#pragma unroll
            for (int s = 0; s < 4; ++s) {
                oL[mt] = __builtin_amdgcn_mfma_f32_32x32x16_f16(vf[s][0], pa[s], oL[mt], 0, 0, 0);
                oH[mt] = __builtin_amdgcn_mfma_f32_32x32x16_f16(vf[s][1], pa[s], oH[mt], 0, 0, 0);
                ol[mt] = __builtin_amdgcn_mfma_f32_32x32x16_f16(ones,     pa[s], ol[mt], 0, 0, 0);
            }
            __builtin_amdgcn_s_setprio(0);
        }

        __syncthreads();   // drains prefetch DMA (vmcnt) + LDS
    }

    // ---- epilogue: o reg r holds O[d = (r&3)+8*(r>>2)+4*hi (+32 for oH)][q].
    //      l = ol[mt][0] (MFMA summed both hi-halves). Ap stored NORMALIZED. ----
    _Float16* Ab = Ap + (size_t)ks * APART + ((size_t)b * kSQ + qb) * kD;
    float2* MLb = MLp + (size_t)ks * kB * kSQ + (size_t)b * kSQ + qb;
#pragma unroll
    for (int mt = 0; mt < MT; ++mt) {
        const int q = w * 64 + mt * 32 + l31;
        const float lf = ol[mt][0];
        const float inv = 1.0f / lf;
        _Float16* arow = &Ab[(size_t)q * kD];
#pragma unroll
        for (int g = 0; g < 4; ++g) {
            *(f16x4*)&arow[g * 8 + hi * 4] =
                pack4(oL[mt][4 * g] * inv, oL[mt][4 * g + 1] * inv,
                      oL[mt][4 * g + 2] * inv, oL[mt][4 * g + 3] * inv);
            *(f16x4*)&arow[32 + g * 8 + hi * 4] =
                pack4(oH[mt][4 * g] * inv, oH[mt][4 * g + 1] * inv,
                      oH[mt][4 * g + 2] * inv, oH[mt][4 * g + 3] * inv);
        }
        if (hi == 0) MLb[q] = make_float2(m_i[mt], lf);
    }
}

// ---------------- combine (exp2 domain; Ap normalized, weight = e*l) ----------------
__global__ __launch_bounds__(256)
void fattn_combine(const _Float16* __restrict__ Ap,
                   const float2* __restrict__ MLp,
                   float* __restrict__ Og)
{
    const int idx = blockIdx.x * 256 + threadIdx.x;
    const int r = idx >> 4;
    const int c = (idx & 15) * 4;

    float m = -1e30f;
    float2 ml[KSPLIT];
#pragma unroll
    for (int s = 0; s < KSPLIT; ++s) {
        ml[s] = MLp[(size_t)s * kB * kSQ + r];
        m = fmaxf(m, ml[s].x);
    }
    float acc[4] = {0.f, 0.f, 0.f, 0.f};
    float lsum = 0.f;
#pragma unroll
    for (int s = 0; s < KSPLIT; ++s) {
        const float wgt = __builtin_amdgcn_exp2f(ml[s].x - m) * ml[s].y;
        lsum += wgt;
        const f16x4 a = *(const f16x4*)&Ap[(size_t)s * APART + (size_t)r * kD + c];
#pragma unroll
        for (int j = 0; j < 4; ++j) acc[j] += wgt * (float)a[j];
    }
    const float inv = 1.0f / lsum;
    float4 res = make_float4(acc[0] * inv, acc[1] * inv, acc[2] * inv, acc[3] * inv);
    *(float4*)&Og[(size_t)r * kD + c] = res;
}

extern "C" void kernel_launch(void* const* d_in, const int* in_sizes, int n_in,
                              void* d_out, int out_size, void* d_ws, size_t ws_size,
                              hipStream_t stream) {
    const float* Q    = (const float*)d_in[0];
    const float* K    = (const float*)d_in[1];
    const float* V    = (const float*)d_in[2];
    const float* sdiv = (const float*)d_in[4];
    float* O = (float*)d_out;

    // workspace: Kh 4MB | Vt 4MB | Ap fp16 16.8MB | MLp 1MB
    _Float16* Kh  = (_Float16*)d_ws;
    _Float16* Vt  = Kh + (size_t)kB * kSK * kD;
    _Float16* Ap  = Vt + (size_t)kB * kSK * kD;
    float2*   MLp = (float2*)(Ap + (size_t)KSPLIT * APART);

    fattn_prepass<<<dim3(kSK / BK, kB), dim3(256), 0, stream>>>(K, V, Kh, Vt);
    fattn_partial<<<dim3((kSQ / BQ) * kB * KSPLIT), dim3(256), 0, stream>>>(Q, Kh, Vt, sdiv, Ap, MLp);
    fattn_combine<<<dim3(kB * kSQ * kD / (256 * 4)), dim3(256), 0, stream>>>(Ap, MLp, O);
}